// Round 4
// baseline (306.187 us; speedup 1.0000x reference)
//
#include <hip/hip_runtime.h>

// SpectralConv3d: closed-form separable transforms (no FFT needed).
// fwd:  X[bc,k1,k2,k3] = sum_{j1,j2,j3} T[k1,j1]T[k2,j2]T[k3,j3] x[bc,j1,j2,j3]
//       T[k,j] = w_j cos(2*pi*j*k/126), w_0=w_63=1 else 2   (k<16, j<64)
// mix:  low[b,o,m] = sum_i X[b,i,m] W[i,o,m]
// inv:  out_re/im = low contracted with cosA (p1), cosA (p2), cosB/sinB (p3)
//       cosA[p,j]=cos(2pi j p/64)/64 (p<33), cosB/sinB[p,j]=cos/sin(2pi j p/33)/33 (p<17)
//
// Fused forward: each block owns 16 j1-planes of one bc, contracts j3/j2 per
// plane (identical phase1/phase2 as before) and folds the j1 contraction into
// 16 register accumulators, writing partial X directly. A2 (25 MB round-trip)
// and the k_fwd3 launch are gone. k_mix sums the 4 j1-quarter partials.

#define PI2 6.283185307179586476925f

// ---------------- fused forward: j3, j2, and j1 contraction ----------------
__global__ __launch_bounds__(256) void k_fwd(const float* __restrict__ x,
                                             float* __restrict__ Xp,   // [4][128][4096]
                                             float* __restrict__ cA,
                                             float* __restrict__ cB,
                                             float* __restrict__ sB) {
    __shared__ float xt[64 * 68];   // [j2][j3] padded stride 68 (17 float4)
    __shared__ float Ts[16 * 68];   // T[k][j], padded
    __shared__ float tmp[16 * 68];  // tmp[k3][j2], padded
    const int j1q = blockIdx.x;     // 0..3 -> j1 in [16*j1q, 16*j1q+16)
    const int bc = blockIdx.y;      // 0..127
    const int t = threadIdx.x;

    float4* xt4 = (float4*)xt;
    float4* Ts4 = (float4*)Ts;

    // prefetch tile 0 (issued before the cosf table work to hide latency)
    const float4* xg = (const float4*)x + ((size_t)bc * 64 + j1q * 16) * 1024;
    float4 buf[4], nxt[4];
#pragma unroll
    for (int c = 0; c < 4; c++) buf[c] = xg[c * 256 + t];

    // compute T tile in-LDS (bit-identical to original k_init formula)
    {
        int k = t >> 4, q = t & 15;
        float4 tv;
        float* tp = (float*)&tv;
#pragma unroll
        for (int e = 0; e < 4; e++) {
            int j = 4 * q + e;
            float w = (j == 0 || j == 63) ? 1.f : 2.f;
            int r = (j * k) % 126;
            tp[e] = w * cosf(PI2 * (float)r / 126.f);
        }
        Ts4[k * 17 + q] = tv;
    }
    // one block publishes the inverse-transform tables for k_inv
    if (j1q == 0 && bc == 0) {
        for (int c = t; c < 528; c += 256) {
            int p = c >> 4, j = c & 15;
            int r = (j * p) % 64;
            cA[c] = cosf(PI2 * (float)r / 64.f) * (1.f / 64.f);
        }
        for (int c = t; c < 272; c += 256) {
            int p = c >> 4, j = c & 15;
            int r = (j * p) % 33;
            float a = PI2 * (float)r / 33.f;
            cB[c] = cosf(a) * (1.f / 33.f);
            sB[c] = sinf(a) * (1.f / 33.f);
        }
    }

    float acc[16];
#pragma unroll
    for (int k1 = 0; k1 < 16; k1++) acc[k1] = 0.f;

    for (int i = 0; i < 16; i++) {
        // issue next-tile loads; they land during this tile's compute
        if (i < 15) {
#pragma unroll
            for (int c = 0; c < 4; c++) nxt[c] = xg[(i + 1) * 1024 + c * 256 + t];
        }
        // stage tile i into LDS
#pragma unroll
        for (int c = 0; c < 4; c++) {
            int e = c * 256 + t;
            xt4[(e >> 4) * 17 + (e & 15)] = buf[c];
        }
        __syncthreads();

        // phase 1: tmp[k3][j2] = sum_j3 xt[j2][j3] * T[k3][j3]  (2x2 blocking)
        {
            const int j2l = t & 31;
            const int k3l = t >> 5;   // 0..7
            float a00 = 0.f, a01 = 0.f, a10 = 0.f, a11 = 0.f;
#pragma unroll 4
            for (int q = 0; q < 16; q++) {
                float4 x0 = xt4[j2l * 17 + q];
                float4 x1 = xt4[(j2l + 32) * 17 + q];
                float4 t0 = Ts4[k3l * 17 + q];
                float4 t1 = Ts4[(k3l + 8) * 17 + q];
                a00 += x0.x * t0.x + x0.y * t0.y + x0.z * t0.z + x0.w * t0.w;
                a01 += x0.x * t1.x + x0.y * t1.y + x0.z * t1.z + x0.w * t1.w;
                a10 += x1.x * t0.x + x1.y * t0.y + x1.z * t0.z + x1.w * t0.w;
                a11 += x1.x * t1.x + x1.y * t1.y + x1.z * t1.z + x1.w * t1.w;
            }
            tmp[k3l * 68 + j2l] = a00;
            tmp[(k3l + 8) * 68 + j2l] = a01;
            tmp[k3l * 68 + j2l + 32] = a10;
            tmp[(k3l + 8) * 68 + j2l + 32] = a11;
        }
        __syncthreads();

        // phase 2: a2[k2][k3] = sum_j2 tmp[k3][j2] * T[k2][j2]; fold into acc[k1]
        {
            const int k3 = t & 15;
            const int k2 = t >> 4;
            const float4* tmp4 = (const float4*)tmp;
            float a2 = 0.f;
#pragma unroll 4
            for (int q = 0; q < 16; q++) {
                float4 tv = tmp4[k3 * 17 + q];
                float4 Tv = Ts4[k2 * 17 + q];
                a2 += tv.x * Tv.x + tv.y * Tv.y + tv.z * Tv.z + tv.w * Tv.w;
            }
            const int j1 = j1q * 16 + i;   // uniform -> broadcast LDS reads
#pragma unroll
            for (int k1 = 0; k1 < 16; k1++) acc[k1] += a2 * Ts[k1 * 68 + j1];
        }
#pragma unroll
        for (int c = 0; c < 4; c++) buf[c] = nxt[c];
        // no barrier needed here: next stage writes xt (phase1 readers already
        // barrier'd), next phase1's tmp write is guarded by the next barrier.
    }

    // write partial X for this j1-quarter: Xp[j1q][bc][k1][t]
    float* Xo = Xp + (size_t)j1q * 524288 + (size_t)bc * 4096 + t;
#pragma unroll
    for (int k1 = 0; k1 < 16; k1++) Xo[(size_t)k1 * 256] = acc[k1];
}

// ---------------- channel mix ----------------
// low[b,o,m] = sum_i (sum_q Xp[q][b*32+i][m]) * W[(i*32+o)][m]
// 2 o's per block; W read exactly once; Xp partials are L2/L3-resident.
__global__ __launch_bounds__(256) void k_mix(const float* __restrict__ Xp,
                                             const float* __restrict__ W,
                                             float* __restrict__ low) {
    const int mc = blockIdx.x;   // 0..15
    const int og = blockIdx.y;   // 0..15 -> o = 2*og, 2*og+1
    const int m = mc * 256 + threadIdx.x;
    const float* Xb = Xp + m;
    const float* Wp = W + (size_t)(og * 2) * 4096 + m;
    float acc[4][2] = {{0.f,0.f},{0.f,0.f},{0.f,0.f},{0.f,0.f}};
#pragma unroll 4
    for (int i = 0; i < 32; i++) {
        float w0 = Wp[(size_t)(i * 32) * 4096];
        float w1 = Wp[(size_t)(i * 32 + 1) * 4096];
#pragma unroll
        for (int b = 0; b < 4; b++) {
            size_t off = (size_t)(b * 32 + i) * 4096;
            float xv = (Xb[off] + Xb[524288 + off]) +
                       (Xb[1048576 + off] + Xb[1572864 + off]);
            acc[b][0] += xv * w0;
            acc[b][1] += xv * w1;
        }
    }
#pragma unroll
    for (int b = 0; b < 4; b++) {
        low[((size_t)(b * 32 + og * 2)) * 4096 + m] = acc[b][0];
        low[((size_t)(b * 32 + og * 2 + 1)) * 4096 + m] = acc[b][1];
    }
}

// ---------------- fused inverse, 3 p1 per block ----------------
__global__ __launch_bounds__(256) void k_inv(const float* __restrict__ low,
                                             const float* __restrict__ cA,
                                             const float* __restrict__ cB,
                                             const float* __restrict__ sB,
                                             float* __restrict__ out) {
    __shared__ float lt[4096];
    __shared__ float c1[3 * 256];
    __shared__ float c2[3 * 528];
    __shared__ float cAs[528], cBs[272], sBs[272];
    const int p1b = blockIdx.x * 3;   // 0,3,...,30 (11 blocks -> 33 p1)
    const int bo = blockIdx.y;
    const int t = threadIdx.x;

    float4* lt4 = (float4*)lt;
    const float4* lg = (const float4*)(low + (size_t)bo * 4096);
    for (int c = t; c < 1024; c += 256) lt4[c] = lg[c];
    for (int c = t; c < 528; c += 256) cAs[c] = cA[c];
    for (int c = t; c < 272; c += 256) { cBs[c] = cB[c]; sBs[c] = sB[c]; }
    __syncthreads();

    // E: c1[s][k2*16+k3] = sum_k1 low[k1][k2k3] * cosA[p1b+s][k1]  (lt read once)
    {
        float e0 = 0.f, e1 = 0.f, e2 = 0.f;
#pragma unroll
        for (int k1 = 0; k1 < 16; k1++) {
            float v = lt[(k1 << 8) + t];
            e0 += v * cAs[(p1b + 0) * 16 + k1];
            e1 += v * cAs[(p1b + 1) * 16 + k1];
            e2 += v * cAs[(p1b + 2) * 16 + k1];
        }
        c1[t] = e0; c1[256 + t] = e1; c1[512 + t] = e2;
    }
    __syncthreads();

    // F: c2[s][p2*16+k3] = sum_k2 c1[s][k2*16+k3] * cosA[p2][k2]
    for (int idx = t; idx < 528; idx += 256) {
        int p2 = idx >> 4, k3 = idx & 15;
        float f0 = 0.f, f1 = 0.f, f2 = 0.f;
#pragma unroll
        for (int k2 = 0; k2 < 16; k2++) {
            float cv = cAs[p2 * 16 + k2];
            int a = (k2 << 4) + k3;
            f0 += c1[a] * cv;
            f1 += c1[256 + a] * cv;
            f2 += c1[512 + a] * cv;
        }
        c2[idx] = f0; c2[528 + idx] = f1; c2[1056 + idx] = f2;
    }
    __syncthreads();

    // G: out[p1b+s][p2][p3][{re,im}] = sum_k3 c2[s][p2][k3] * cosB/sinB[p3][k3]
    for (int s = 0; s < 3; s++) {
        float* op = out + ((size_t)bo * 33 + p1b + s) * 33 * 17 * 2;
        const float* c2p = c2 + s * 528;
        for (int idx = t; idx < 1122; idx += 256) {
            int p2 = idx / 34, rem = idx - p2 * 34;
            int p3 = rem >> 1, cc = rem & 1;
            const float* M = cc ? sBs : cBs;
            float acc = 0.f;
#pragma unroll
            for (int k3 = 0; k3 < 16; k3++) acc += c2p[(p2 << 4) + k3] * M[p3 * 16 + k3];
            op[idx] = acc;
        }
    }
}

extern "C" void kernel_launch(void* const* d_in, const int* in_sizes, int n_in,
                              void* d_out, int out_size, void* d_ws, size_t ws_size,
                              hipStream_t stream) {
    const float* x = (const float*)d_in[0];   // (4,32,64,64,64)
    const float* W = (const float*)d_in[1];   // (32,32,16,16,16)
    float* out = (float*)d_out;               // (4,32,33,33,17,2)

    float* ws = (float*)d_ws;
    float* cA   = ws;                 // 528
    float* cB   = ws + 528;           // 272
    float* sB   = ws + 800;           // 272
    float* Xp   = ws + 4096;          // 4 partials: 4*128*4096 = 2097152
    float* low  = Xp + 2097152;       // 128*4096   = 524288

    k_fwd<<<dim3(4, 128), dim3(256), 0, stream>>>(x, Xp, cA, cB, sB);
    k_mix<<<dim3(16, 16), dim3(256), 0, stream>>>(Xp, W, low);
    k_inv<<<dim3(11, 128), dim3(256), 0, stream>>>(low, cA, cB, sB, out);
}

// Round 5
// 240.373 us; speedup vs baseline: 1.2738x; 1.2738x over previous
//
#include <hip/hip_runtime.h>

// SpectralConv3d: closed-form separable transforms (no FFT needed).
// fwd:  X[bc,k1,k2,k3] = sum_{j1,j2,j3} T[k1,j1]T[k2,j2]T[k3,j3] x[bc,j1,j2,j3]
//       T[k,j] = w_j cos(2*pi*j*k/126), w_0=w_63=1 else 2   (k<16, j<64)
// mix:  low[b,o,m] = sum_i X[b,i,m] W[i,o,m]
// inv:  out_re/im = low contracted with cosA (p1), cosA (p2), cosB/sinB (p3)
//       cosA[p,j]=cos(2pi j p/64)/64 (p<33), cosB/sinB[p,j]=cos/sin(2pi j p/33)/33 (p<17)
//
// Round-3 structure (best measured: 239.2). fwd12 now 512 threads/block:
// same 26.1 KB LDS -> 4 blocks/CU x 8 waves = 32 waves/CU (was 24), more MLP
// during the x-stream. Per-output FMA chains identical -> bit-identical result.

#define PI2 6.283185307179586476925f

// ---------------- fused forward: contract j3 then j2 per (bc, j1) ----------------
__global__ __launch_bounds__(512) void k_fwd12(const float* __restrict__ x,
                                               float* __restrict__ A2,
                                               float* __restrict__ cA,
                                               float* __restrict__ cB,
                                               float* __restrict__ sB) {
    __shared__ float xt[64 * 68];   // [j2][j3] padded stride 68 (17 float4)
    __shared__ float Ts[16 * 68];
    __shared__ float tmp[16 * 68];  // tmp[k3][j2], padded
    const int j1 = blockIdx.x, bc = blockIdx.y;
    const int t = threadIdx.x;      // 0..511

    float4* xt4 = (float4*)xt;
    float4* Ts4 = (float4*)Ts;
    const float4* xg = (const float4*)(x + ((size_t)bc * 64 + j1) * 4096);
    for (int c = t; c < 1024; c += 512) {
        int j2 = c >> 4, q = c & 15;
        xt4[j2 * 17 + q] = xg[c];
    }
    // compute T tile in-LDS (bit-identical to the original k_init formula)
    if (t < 256) {
        int k = t >> 4, q = t & 15;
        float4 tv;
        float* tp = (float*)&tv;
#pragma unroll
        for (int e = 0; e < 4; e++) {
            int j = 4 * q + e;
            float w = (j == 0 || j == 63) ? 1.f : 2.f;
            int r = (j * k) % 126;
            tp[e] = w * cosf(PI2 * (float)r / 126.f);
        }
        Ts4[k * 17 + q] = tv;
    }
    // one block publishes the inverse-transform tables for k_inv
    if (j1 == 0 && bc == 0) {
        for (int c = t; c < 528; c += 512) {
            int p = c >> 4, j = c & 15;
            int r = (j * p) % 64;
            cA[c] = cosf(PI2 * (float)r / 64.f) * (1.f / 64.f);
        }
        if (t < 272) {
            int p = t >> 4, j = t & 15;
            int r = (j * p) % 33;
            float a = PI2 * (float)r / 33.f;
            cB[t] = cosf(a) * (1.f / 33.f);
            sB[t] = sinf(a) * (1.f / 33.f);
        }
    }
    __syncthreads();

    // phase 1: tmp[k3][j2] = sum_j3 xt[j2][j3] * T[k3][j3]
    // 512 threads: thread owns j2 in {j2l, j2l+32}, single k3 = t>>5 (0..15).
    {
        const int j2l = t & 31;
        const int k3 = t >> 5;   // 0..15
        float a0 = 0.f, a1 = 0.f;
#pragma unroll 4
        for (int q = 0; q < 16; q++) {
            float4 x0 = xt4[j2l * 17 + q];
            float4 x1 = xt4[(j2l + 32) * 17 + q];
            float4 t0 = Ts4[k3 * 17 + q];
            a0 += x0.x * t0.x + x0.y * t0.y + x0.z * t0.z + x0.w * t0.w;
            a1 += x1.x * t0.x + x1.y * t0.y + x1.z * t0.z + x1.w * t0.w;
        }
        tmp[k3 * 68 + j2l] = a0;
        tmp[k3 * 68 + j2l + 32] = a1;
    }
    __syncthreads();

    // phase 2: A2[k2][k3] = sum_j2 tmp[k3][j2] * T[k2][j2]  (threads 0..255)
    if (t < 256) {
        const int k3 = t & 15;
        const int k2 = t >> 4;
        const float4* tmp4 = (const float4*)tmp;
        float acc = 0.f;
#pragma unroll 4
        for (int q = 0; q < 16; q++) {
            float4 tv = tmp4[k3 * 17 + q];
            float4 Tv = Ts4[k2 * 17 + q];
            acc += tv.x * Tv.x + tv.y * Tv.y + tv.z * Tv.z + tv.w * Tv.w;
        }
        A2[((size_t)bc * 64 + j1) * 256 + t] = acc;  // k2*16+k3 == t, coalesced
    }
}

// ---------------- forward j1 contraction ----------------
// X[bc][k1][m23] = sum_j1 A2[bc][j1][m23] * T[k1][j1]
// 8 k1-accumulators per thread; Tst computed in-LDS (bit-identical cosf).
__global__ __launch_bounds__(256) void k_fwd3(const float* __restrict__ A2,
                                              float* __restrict__ X) {
    __shared__ float Tst[512];  // [j1][c], c = k1 - 8*k1h
    const int k1h = blockIdx.x;  // 0..1
    const int bc = blockIdx.y;
    const int t = threadIdx.x;
    for (int c0 = t; c0 < 512; c0 += 256) {
        int j1 = c0 >> 3, c = c0 & 7;
        int k1 = k1h * 8 + c;
        float w = (j1 == 0 || j1 == 63) ? 1.f : 2.f;
        int r = (j1 * k1) % 126;
        Tst[c0] = w * cosf(PI2 * (float)r / 126.f);
    }
    __syncthreads();
    const float* Ap = A2 + (size_t)bc * 64 * 256 + t;
    float acc[8] = {0.f, 0.f, 0.f, 0.f, 0.f, 0.f, 0.f, 0.f};
#pragma unroll 8
    for (int j1 = 0; j1 < 64; j1++) {
        float v = Ap[j1 * 256];
        float4 t0 = *(const float4*)&Tst[j1 * 8];
        float4 t1 = *(const float4*)&Tst[j1 * 8 + 4];
        acc[0] += v * t0.x; acc[1] += v * t0.y; acc[2] += v * t0.z; acc[3] += v * t0.w;
        acc[4] += v * t1.x; acc[5] += v * t1.y; acc[6] += v * t1.z; acc[7] += v * t1.w;
    }
    float* Xp = X + (size_t)bc * 4096 + (size_t)(k1h * 8) * 256 + t;
#pragma unroll
    for (int c = 0; c < 8; c++) Xp[(size_t)c * 256] = acc[c];
}

// ---------------- channel mix ----------------
// low[b,o,m] = sum_i X[b*32+i][m] * W[(i*32+o)][m]
// 2 o's per block: X re-reads halved, W still read exactly once.
__global__ __launch_bounds__(256) void k_mix(const float* __restrict__ X,
                                             const float* __restrict__ W,
                                             float* __restrict__ low) {
    const int mc = blockIdx.x;   // 0..15
    const int og = blockIdx.y;   // 0..15 -> o = 2*og, 2*og+1
    const int m = mc * 256 + threadIdx.x;
    const float* Xp = X + m;
    const float* Wp = W + (size_t)(og * 2) * 4096 + m;
    float acc[4][2] = {{0.f,0.f},{0.f,0.f},{0.f,0.f},{0.f,0.f}};
#pragma unroll 4
    for (int i = 0; i < 32; i++) {
        float w0 = Wp[(size_t)(i * 32) * 4096];
        float w1 = Wp[(size_t)(i * 32 + 1) * 4096];
#pragma unroll
        for (int b = 0; b < 4; b++) {
            float xv = Xp[(size_t)(b * 32 + i) * 4096];
            acc[b][0] += xv * w0;
            acc[b][1] += xv * w1;
        }
    }
#pragma unroll
    for (int b = 0; b < 4; b++) {
        low[((size_t)(b * 32 + og * 2)) * 4096 + m] = acc[b][0];
        low[((size_t)(b * 32 + og * 2 + 1)) * 4096 + m] = acc[b][1];
    }
}

// ---------------- fused inverse, 3 p1 per block ----------------
__global__ __launch_bounds__(256) void k_inv(const float* __restrict__ low,
                                             const float* __restrict__ cA,
                                             const float* __restrict__ cB,
                                             const float* __restrict__ sB,
                                             float* __restrict__ out) {
    __shared__ float lt[4096];
    __shared__ float c1[3 * 256];
    __shared__ float c2[3 * 528];
    __shared__ float cAs[528], cBs[272], sBs[272];
    const int p1b = blockIdx.x * 3;   // 0,3,...,30 (11 blocks -> 33 p1)
    const int bo = blockIdx.y;
    const int t = threadIdx.x;

    float4* lt4 = (float4*)lt;
    const float4* lg = (const float4*)(low + (size_t)bo * 4096);
    for (int c = t; c < 1024; c += 256) lt4[c] = lg[c];
    for (int c = t; c < 528; c += 256) cAs[c] = cA[c];
    for (int c = t; c < 272; c += 256) { cBs[c] = cB[c]; sBs[c] = sB[c]; }
    __syncthreads();

    // E: c1[s][k2*16+k3] = sum_k1 low[k1][k2k3] * cosA[p1b+s][k1]  (lt read once)
    {
        float e0 = 0.f, e1 = 0.f, e2 = 0.f;
#pragma unroll
        for (int k1 = 0; k1 < 16; k1++) {
            float v = lt[(k1 << 8) + t];
            e0 += v * cAs[(p1b + 0) * 16 + k1];
            e1 += v * cAs[(p1b + 1) * 16 + k1];
            e2 += v * cAs[(p1b + 2) * 16 + k1];
        }
        c1[t] = e0; c1[256 + t] = e1; c1[512 + t] = e2;
    }
    __syncthreads();

    // F: c2[s][p2*16+k3] = sum_k2 c1[s][k2*16+k3] * cosA[p2][k2]
    for (int idx = t; idx < 528; idx += 256) {
        int p2 = idx >> 4, k3 = idx & 15;
        float f0 = 0.f, f1 = 0.f, f2 = 0.f;
#pragma unroll
        for (int k2 = 0; k2 < 16; k2++) {
            float cv = cAs[p2 * 16 + k2];
            int a = (k2 << 4) + k3;
            f0 += c1[a] * cv;
            f1 += c1[256 + a] * cv;
            f2 += c1[512 + a] * cv;
        }
        c2[idx] = f0; c2[528 + idx] = f1; c2[1056 + idx] = f2;
    }
    __syncthreads();

    // G: out[p1b+s][p2][p3][{re,im}] = sum_k3 c2[s][p2][k3] * cosB/sinB[p3][k3]
    for (int s = 0; s < 3; s++) {
        float* op = out + ((size_t)bo * 33 + p1b + s) * 33 * 17 * 2;
        const float* c2p = c2 + s * 528;
        for (int idx = t; idx < 1122; idx += 256) {
            int p2 = idx / 34, rem = idx - p2 * 34;
            int p3 = rem >> 1, cc = rem & 1;
            const float* M = cc ? sBs : cBs;
            float acc = 0.f;
#pragma unroll
            for (int k3 = 0; k3 < 16; k3++) acc += c2p[(p2 << 4) + k3] * M[p3 * 16 + k3];
            op[idx] = acc;
        }
    }
}

extern "C" void kernel_launch(void* const* d_in, const int* in_sizes, int n_in,
                              void* d_out, int out_size, void* d_ws, size_t ws_size,
                              hipStream_t stream) {
    const float* x = (const float*)d_in[0];   // (4,32,64,64,64)
    const float* W = (const float*)d_in[1];   // (32,32,16,16,16)
    float* out = (float*)d_out;               // (4,32,33,33,17,2)

    float* ws = (float*)d_ws;
    float* cA   = ws;                 // 528
    float* cB   = ws + 528;           // 272
    float* sB   = ws + 800;           // 272
    float* A2   = ws + 4096;          // 128*64*256 = 2097152
    float* X    = A2 + 2097152;       // 128*4096   = 524288
    float* low  = X + 524288;         // 128*4096   = 524288

    k_fwd12<<<dim3(64, 128), dim3(512), 0, stream>>>(x, A2, cA, cB, sB);
    k_fwd3<<<dim3(2, 128), dim3(256), 0, stream>>>(A2, X);
    k_mix<<<dim3(16, 16), dim3(256), 0, stream>>>(X, W, low);
    k_inv<<<dim3(11, 128), dim3(256), 0, stream>>>(low, cA, cB, sB, out);
}